// Round 1
// baseline (762.814 us; speedup 1.0000x reference)
//
#include <hip/hip_runtime.h>
#include <hip/hip_bf16.h>

#define NNODES 50000
#define NEDGES 800000
#define EPLUS  (NEDGES + NNODES)   // edges incl. self-loops = 850000
#define INC    128
#define HID    64
#define NHEADS 4
#define OUTC   64
#define NEG_SLOPE 0.2f

// ---------------- CSR build ----------------

__global__ void k_count(const int* __restrict__ ei, int* __restrict__ cnt) {
    int e = blockIdx.x * blockDim.x + threadIdx.x;
    if (e >= EPLUS) return;
    int dst = (e < NEDGES) ? ei[NEDGES + e] : (e - NEDGES);
    atomicAdd(&cnt[dst], 1);
}

// single-block exclusive scan over cnt[0..NNODES-1], writes cnt[NNODES] = total
__global__ void k_scan(int* __restrict__ cnt) {
    const int T = 1024;
    __shared__ int sums[T];
    int t = threadIdx.x;
    int L = (NNODES + T - 1) / T;            // 49
    int s0 = t * L;
    int s1 = s0 + L; if (s1 > NNODES) s1 = NNODES;
    int local = 0;
    for (int i = s0; i < s1; i++) local += cnt[i];
    sums[t] = local;
    __syncthreads();
    for (int off = 1; off < T; off <<= 1) {
        int v = (t >= off) ? sums[t - off] : 0;
        __syncthreads();
        sums[t] += v;
        __syncthreads();
    }
    int run = (t == 0) ? 0 : sums[t - 1];    // exclusive prefix
    for (int i = s0; i < s1; i++) { int c = cnt[i]; cnt[i] = run; run += c; }
    if (t == T - 1) cnt[NNODES] = sums[T - 1];
}

__global__ void k_copy_int(const int* __restrict__ src, int* __restrict__ dst, int n) {
    int i = blockIdx.x * blockDim.x + threadIdx.x;
    if (i < n) dst[i] = src[i];
}

__global__ void k_scatter(const int* __restrict__ ei, int* __restrict__ cursor,
                          int* __restrict__ col_src) {
    int e = blockIdx.x * blockDim.x + threadIdx.x;
    if (e >= EPLUS) return;
    int src, dst;
    if (e < NEDGES) { src = ei[e]; dst = ei[NEDGES + e]; }
    else            { src = dst = e - NEDGES; }
    int pos = atomicAdd(&cursor[dst], 1);
    col_src[pos] = src;
}

// ---------------- fp32 tiled GEMM: C[M,NCOL] = A[M,K] @ B[K,NCOL] ----------------
// BM=64 BN=64 BK=32, 256 threads, 4x4 micro-tile per thread.

template <int K, int NCOL>
__global__ void k_gemm(const float* __restrict__ A, const float* __restrict__ B,
                       float* __restrict__ C, int M) {
    __shared__ float As[64][33];
    __shared__ float Bs[32][64];
    int tid = threadIdx.x;
    int row0 = blockIdx.x * 64;
    int col0 = blockIdx.y * 64;
    int tx = tid & 15, ty = tid >> 4;

    float acc[4][4];
#pragma unroll
    for (int i = 0; i < 4; i++)
#pragma unroll
        for (int j = 0; j < 4; j++) acc[i][j] = 0.f;

    int ar = tid >> 2, ac = (tid & 3) << 3;   // A: 8 consecutive floats
    int br = tid >> 3, bc = (tid & 7) << 3;   // B: 8 consecutive floats

    for (int k0 = 0; k0 < K; k0 += 32) {
        int grow = row0 + ar;
        if (grow < M) {
            const float* ap = A + (size_t)grow * K + k0 + ac;
            float4 a0 = *(const float4*)ap;
            float4 a1 = *(const float4*)(ap + 4);
            As[ar][ac + 0] = a0.x; As[ar][ac + 1] = a0.y; As[ar][ac + 2] = a0.z; As[ar][ac + 3] = a0.w;
            As[ar][ac + 4] = a1.x; As[ar][ac + 5] = a1.y; As[ar][ac + 6] = a1.z; As[ar][ac + 7] = a1.w;
        } else {
#pragma unroll
            for (int j = 0; j < 8; j++) As[ar][ac + j] = 0.f;
        }
        {
            const float* bp = B + (size_t)(k0 + br) * NCOL + col0 + bc;
            float4 b0 = *(const float4*)bp;
            float4 b1 = *(const float4*)(bp + 4);
            Bs[br][bc + 0] = b0.x; Bs[br][bc + 1] = b0.y; Bs[br][bc + 2] = b0.z; Bs[br][bc + 3] = b0.w;
            Bs[br][bc + 4] = b1.x; Bs[br][bc + 5] = b1.y; Bs[br][bc + 6] = b1.z; Bs[br][bc + 7] = b1.w;
        }
        __syncthreads();
#pragma unroll
        for (int kk = 0; kk < 32; kk++) {
            float a[4];
#pragma unroll
            for (int i = 0; i < 4; i++) a[i] = As[ty * 4 + i][kk];
            float4 bv = *(const float4*)&Bs[kk][tx * 4];
            float b[4] = {bv.x, bv.y, bv.z, bv.w};
#pragma unroll
            for (int i = 0; i < 4; i++)
#pragma unroll
                for (int j = 0; j < 4; j++) acc[i][j] += a[i] * b[j];
        }
        __syncthreads();
    }
#pragma unroll
    for (int i = 0; i < 4; i++) {
        int r = row0 + ty * 4 + i;
        if (r < M) {
            float4 v = {acc[i][0], acc[i][1], acc[i][2], acc[i][3]};
            *(float4*)&C[(size_t)r * NCOL + col0 + tx * 4] = v;
        }
    }
}

// ---------------- attention logits ----------------

__global__ void k_alpha1(const float* __restrict__ h1, const float* __restrict__ a_src,
                         const float* __restrict__ a_dst, float* __restrict__ as,
                         float* __restrict__ ad) {
    int i = blockIdx.x * blockDim.x + threadIdx.x;
    if (i >= NNODES * NHEADS) return;
    int n = i / NHEADS, h = i % NHEADS;
    const float* hp = h1 + (size_t)n * (NHEADS * HID) + h * HID;
    const float* ps = a_src + h * HID;
    const float* pd = a_dst + h * HID;
    float s = 0.f, d = 0.f;
#pragma unroll 8
    for (int c = 0; c < HID; c++) { float v = hp[c]; s += v * ps[c]; d += v * pd[c]; }
    as[i] = s; ad[i] = d;
}

__global__ void k_alpha2(const float* __restrict__ h2, const float* __restrict__ a_src,
                         const float* __restrict__ a_dst, float* __restrict__ as,
                         float* __restrict__ ad) {
    int n = blockIdx.x * blockDim.x + threadIdx.x;
    if (n >= NNODES) return;
    const float* hp = h2 + (size_t)n * OUTC;
    float s = 0.f, d = 0.f;
#pragma unroll 8
    for (int c = 0; c < OUTC; c++) { float v = hp[c]; s += v * a_src[c]; d += v * a_dst[c]; }
    as[n] = s; ad[n] = d;
}

// ---------------- segment softmax + aggregate ----------------
// layer 1: one block per node, wave w handles head w; lane = channel.

__global__ void k_agg1(const float* __restrict__ h1, const int* __restrict__ row_ptr,
                       const int* __restrict__ col_src, const float* __restrict__ as,
                       const float* __restrict__ ad, const float* __restrict__ b1,
                       float* __restrict__ out1) {
    int n = blockIdx.x;
    int h = threadIdx.x >> 6;
    int lane = threadIdx.x & 63;
    int beg = row_ptr[n], end = row_ptr[n + 1];
    float adv = ad[n * NHEADS + h];

    float m = -1e30f;
    for (int j = beg; j < end; j++) {
        int s = col_src[j];
        float e = as[s * NHEADS + h] + adv;
        e = (e > 0.f) ? e : NEG_SLOPE * e;
        m = fmaxf(m, e);
    }
    float denom = 0.f, acc = 0.f;
    for (int j = beg; j < end; j++) {
        int s = col_src[j];
        float e = as[s * NHEADS + h] + adv;
        e = (e > 0.f) ? e : NEG_SLOPE * e;
        float ex = __expf(e - m);
        denom += ex;
        acc += ex * h1[(size_t)s * (NHEADS * HID) + h * HID + lane];
    }
    float r = acc / (denom + 1e-16f) + b1[h * HID + lane];
    out1[(size_t)n * (NHEADS * HID) + h * HID + lane] = (r > 0.f) ? r : (__expf(r) - 1.f);
}

// layer 2: heads=1, 4 nodes per block (one wave each); lane = channel.
__global__ void k_agg2(const float* __restrict__ h2, const int* __restrict__ row_ptr,
                       const int* __restrict__ col_src, const float* __restrict__ as,
                       const float* __restrict__ ad, const float* __restrict__ b2,
                       float* __restrict__ out) {
    int n = blockIdx.x * 4 + (threadIdx.x >> 6);
    int lane = threadIdx.x & 63;
    if (n >= NNODES) return;
    int beg = row_ptr[n], end = row_ptr[n + 1];
    float adv = ad[n];

    float m = -1e30f;
    for (int j = beg; j < end; j++) {
        float e = as[col_src[j]] + adv;
        e = (e > 0.f) ? e : NEG_SLOPE * e;
        m = fmaxf(m, e);
    }
    float denom = 0.f, acc = 0.f;
    for (int j = beg; j < end; j++) {
        int s = col_src[j];
        float e = as[s] + adv;
        e = (e > 0.f) ? e : NEG_SLOPE * e;
        float ex = __expf(e - m);
        denom += ex;
        acc += ex * h2[(size_t)s * OUTC + lane];
    }
    out[(size_t)n * OUTC + lane] = acc / (denom + 1e-16f) + b2[lane];
}

// ---------------- launch ----------------

extern "C" void kernel_launch(void* const* d_in, const int* in_sizes, int n_in,
                              void* d_out, int out_size, void* d_ws, size_t ws_size,
                              hipStream_t stream) {
    const float* x   = (const float*)d_in[0];
    const int*   ei  = (const int*)d_in[1];
    const float* W1  = (const float*)d_in[2];
    const float* a1s = (const float*)d_in[3];
    const float* a1d = (const float*)d_in[4];
    const float* b1  = (const float*)d_in[5];
    const float* W2  = (const float*)d_in[6];
    const float* a2s = (const float*)d_in[7];
    const float* a2d = (const float*)d_in[8];
    const float* b2  = (const float*)d_in[9];
    float* out = (float*)d_out;

    char* p = (char*)d_ws;
    auto carve = [&](size_t bytes) -> void* {
        void* r = (void*)p;
        p += (bytes + 255) & ~(size_t)255;
        return r;
    };
    float* h1      = (float*)carve((size_t)NNODES * 256 * 4);
    float* out1    = (float*)carve((size_t)NNODES * 256 * 4);
    float* h2      = (float*)carve((size_t)NNODES * 64 * 4);
    float* as1     = (float*)carve((size_t)NNODES * NHEADS * 4);
    float* ad1     = (float*)carve((size_t)NNODES * NHEADS * 4);
    float* as2     = (float*)carve((size_t)NNODES * 4);
    float* ad2     = (float*)carve((size_t)NNODES * 4);
    int*   row_ptr = (int*)carve((size_t)(NNODES + 1) * 4);
    int*   cursor  = (int*)carve((size_t)NNODES * 4);
    int*   col_src = (int*)carve((size_t)EPLUS * 4);

    // CSR build
    hipMemsetAsync(row_ptr, 0, (size_t)(NNODES + 1) * 4, stream);
    k_count<<<(EPLUS + 255) / 256, 256, 0, stream>>>(ei, row_ptr);
    k_scan<<<1, 1024, 0, stream>>>(row_ptr);
    k_copy_int<<<(NNODES + 255) / 256, 256, 0, stream>>>(row_ptr, cursor, NNODES);
    k_scatter<<<(EPLUS + 255) / 256, 256, 0, stream>>>(ei, cursor, col_src);

    // layer 1
    dim3 g1((NNODES + 63) / 64, 256 / 64);
    k_gemm<INC, 256><<<g1, 256, 0, stream>>>(x, W1, h1, NNODES);
    k_alpha1<<<(NNODES * NHEADS + 255) / 256, 256, 0, stream>>>(h1, a1s, a1d, as1, ad1);
    k_agg1<<<NNODES, 256, 0, stream>>>(h1, row_ptr, col_src, as1, ad1, b1, out1);

    // layer 2
    dim3 g2((NNODES + 63) / 64, 64 / 64);
    k_gemm<256, OUTC><<<g2, 256, 0, stream>>>(out1, W2, h2, NNODES);
    k_alpha2<<<(NNODES + 255) / 256, 256, 0, stream>>>(h2, a2s, a2d, as2, ad2);
    k_agg2<<<(NNODES + 3) / 4, 256, 0, stream>>>(h2, row_ptr, col_src, as2, ad2, b2, out);
}

// Round 2
// 563.729 us; speedup vs baseline: 1.3532x; 1.3532x over previous
//
#include <hip/hip_runtime.h>
#include <hip/hip_bf16.h>

#define NNODES 50000
#define NEDGES 800000
#define EPLUS  (NEDGES + NNODES)   // edges incl. self-loops = 850000
#define INC    128
#define HID    64
#define NHEADS 4
#define OUTC   64
#define NEG_SLOPE 0.2f

// ---------------- CSR build ----------------

__global__ void k_count(const int* __restrict__ ei, int* __restrict__ cnt) {
    int e = blockIdx.x * blockDim.x + threadIdx.x;
    if (e >= EPLUS) return;
    int dst = (e < NEDGES) ? ei[NEDGES + e] : (e - NEDGES);
    atomicAdd(&cnt[dst], 1);
}

// single-block exclusive scan over cnt[0..NNODES-1], writes cnt[NNODES] = total
__global__ void k_scan(int* __restrict__ cnt) {
    const int T = 1024;
    __shared__ int sums[T];
    int t = threadIdx.x;
    int L = (NNODES + T - 1) / T;            // 49
    int s0 = t * L;
    int s1 = s0 + L; if (s1 > NNODES) s1 = NNODES;
    int local = 0;
    for (int i = s0; i < s1; i++) local += cnt[i];
    sums[t] = local;
    __syncthreads();
    for (int off = 1; off < T; off <<= 1) {
        int v = (t >= off) ? sums[t - off] : 0;
        __syncthreads();
        sums[t] += v;
        __syncthreads();
    }
    int run = (t == 0) ? 0 : sums[t - 1];    // exclusive prefix
    for (int i = s0; i < s1; i++) { int c = cnt[i]; cnt[i] = run; run += c; }
    if (t == T - 1) cnt[NNODES] = sums[T - 1];
}

__global__ void k_copy_int(const int* __restrict__ src, int* __restrict__ dst, int n) {
    int i = blockIdx.x * blockDim.x + threadIdx.x;
    if (i < n) dst[i] = src[i];
}

__global__ void k_scatter(const int* __restrict__ ei, int* __restrict__ cursor,
                          int* __restrict__ col_src, int* __restrict__ e_dst) {
    int e = blockIdx.x * blockDim.x + threadIdx.x;
    if (e >= EPLUS) return;
    int src, dst;
    if (e < NEDGES) { src = ei[e]; dst = ei[NEDGES + e]; }
    else            { src = dst = e - NEDGES; }
    int pos = atomicAdd(&cursor[dst], 1);
    col_src[pos] = src;
    e_dst[pos] = dst;
}

// ---------------- fp32 tiled GEMM: C[M,NCOL] = A[M,K] @ B[K,NCOL] ----------------
// BM=64 BN=64 BK=32, 256 threads, 4x4 micro-tile per thread.

template <int K, int NCOL>
__global__ void k_gemm(const float* __restrict__ A, const float* __restrict__ B,
                       float* __restrict__ C, int M) {
    __shared__ float As[64][33];
    __shared__ float Bs[32][64];
    int tid = threadIdx.x;
    int row0 = blockIdx.x * 64;
    int col0 = blockIdx.y * 64;
    int tx = tid & 15, ty = tid >> 4;

    float acc[4][4];
#pragma unroll
    for (int i = 0; i < 4; i++)
#pragma unroll
        for (int j = 0; j < 4; j++) acc[i][j] = 0.f;

    int ar = tid >> 2, ac = (tid & 3) << 3;   // A: 8 consecutive floats
    int br = tid >> 3, bc = (tid & 7) << 3;   // B: 8 consecutive floats

    for (int k0 = 0; k0 < K; k0 += 32) {
        int grow = row0 + ar;
        if (grow < M) {
            const float* ap = A + (size_t)grow * K + k0 + ac;
            float4 a0 = *(const float4*)ap;
            float4 a1 = *(const float4*)(ap + 4);
            As[ar][ac + 0] = a0.x; As[ar][ac + 1] = a0.y; As[ar][ac + 2] = a0.z; As[ar][ac + 3] = a0.w;
            As[ar][ac + 4] = a1.x; As[ar][ac + 5] = a1.y; As[ar][ac + 6] = a1.z; As[ar][ac + 7] = a1.w;
        } else {
#pragma unroll
            for (int j = 0; j < 8; j++) As[ar][ac + j] = 0.f;
        }
        {
            const float* bp = B + (size_t)(k0 + br) * NCOL + col0 + bc;
            float4 b0 = *(const float4*)bp;
            float4 b1 = *(const float4*)(bp + 4);
            Bs[br][bc + 0] = b0.x; Bs[br][bc + 1] = b0.y; Bs[br][bc + 2] = b0.z; Bs[br][bc + 3] = b0.w;
            Bs[br][bc + 4] = b1.x; Bs[br][bc + 5] = b1.y; Bs[br][bc + 6] = b1.z; Bs[br][bc + 7] = b1.w;
        }
        __syncthreads();
#pragma unroll
        for (int kk = 0; kk < 32; kk++) {
            float a[4];
#pragma unroll
            for (int i = 0; i < 4; i++) a[i] = As[ty * 4 + i][kk];
            float4 bv = *(const float4*)&Bs[kk][tx * 4];
            float b[4] = {bv.x, bv.y, bv.z, bv.w};
#pragma unroll
            for (int i = 0; i < 4; i++)
#pragma unroll
                for (int j = 0; j < 4; j++) acc[i][j] += a[i] * b[j];
        }
        __syncthreads();
    }
#pragma unroll
    for (int i = 0; i < 4; i++) {
        int r = row0 + ty * 4 + i;
        if (r < M) {
            float4 v = {acc[i][0], acc[i][1], acc[i][2], acc[i][3]};
            *(float4*)&C[(size_t)r * NCOL + col0 + tx * 4] = v;
        }
    }
}

// ---------------- attention logits ----------------

__global__ void k_alpha1(const float* __restrict__ h1, const float* __restrict__ a_src,
                         const float* __restrict__ a_dst, float* __restrict__ as,
                         float* __restrict__ ad) {
    int i = blockIdx.x * blockDim.x + threadIdx.x;
    if (i >= NNODES * NHEADS) return;
    int n = i / NHEADS, h = i % NHEADS;
    const float* hp = h1 + (size_t)n * (NHEADS * HID) + h * HID;
    const float* ps = a_src + h * HID;
    const float* pd = a_dst + h * HID;
    float s = 0.f, d = 0.f;
#pragma unroll 8
    for (int c = 0; c < HID; c++) { float v = hp[c]; s += v * ps[c]; d += v * pd[c]; }
    as[i] = s; ad[i] = d;
}

__global__ void k_alpha2(const float* __restrict__ h2, const float* __restrict__ a_src,
                         const float* __restrict__ a_dst, float* __restrict__ as,
                         float* __restrict__ ad) {
    int n = blockIdx.x * blockDim.x + threadIdx.x;
    if (n >= NNODES) return;
    const float* hp = h2 + (size_t)n * OUTC;
    float s = 0.f, d = 0.f;
#pragma unroll 8
    for (int c = 0; c < OUTC; c++) { float v = hp[c]; s += v * a_src[c]; d += v * a_dst[c]; }
    as[n] = s; ad[n] = d;
}

// ---------------- edge weights: w = exp(leaky_relu(as[src] + ad[dst])) ----------------
// No max subtraction: logits are O(+-6) (glorot-scaled dots), exp is safe in fp32
// and the normalization below makes the result mathematically identical.

__global__ void k_edgew1(const int* __restrict__ col_src, const int* __restrict__ e_dst,
                         const float* __restrict__ as, const float* __restrict__ ad,
                         float* __restrict__ w) {
    int e = blockIdx.x * blockDim.x + threadIdx.x;
    if (e >= EPLUS) return;
    int s = col_src[e], d = e_dst[e];
    float4 sv = *(const float4*)&as[s * NHEADS];
    float4 dv = *(const float4*)&ad[d * NHEADS];
    float4 r;
    float t;
    t = sv.x + dv.x; t = (t > 0.f) ? t : NEG_SLOPE * t; r.x = __expf(t);
    t = sv.y + dv.y; t = (t > 0.f) ? t : NEG_SLOPE * t; r.y = __expf(t);
    t = sv.z + dv.z; t = (t > 0.f) ? t : NEG_SLOPE * t; r.z = __expf(t);
    t = sv.w + dv.w; t = (t > 0.f) ? t : NEG_SLOPE * t; r.w = __expf(t);
    *(float4*)&w[e * 4] = r;
}

__global__ void k_edgew2(const int* __restrict__ col_src, const int* __restrict__ e_dst,
                         const float* __restrict__ as, const float* __restrict__ ad,
                         float* __restrict__ w) {
    int e = blockIdx.x * blockDim.x + threadIdx.x;
    if (e >= EPLUS) return;
    float t = as[col_src[e]] + ad[e_dst[e]];
    t = (t > 0.f) ? t : NEG_SLOPE * t;
    w[e] = __expf(t);
}

// ---------------- aggregate (weights precomputed) ----------------
// layer 1: one block per node, wave w handles head w; lane = channel.

__global__ void k_agg1(const float* __restrict__ h1, const int* __restrict__ row_ptr,
                       const int* __restrict__ col_src, const float* __restrict__ w,
                       const float* __restrict__ b1, float* __restrict__ out1) {
    int n = blockIdx.x;
    int h = threadIdx.x >> 6;
    int lane = threadIdx.x & 63;
    int beg = row_ptr[n], end = row_ptr[n + 1];
    const float* hp = h1 + h * HID + lane;

    float denom = 0.f, acc = 0.f;
    int j = beg;
    for (; j + 1 < end; j += 2) {
        int s0 = col_src[j], s1 = col_src[j + 1];
        float w0 = w[j * 4 + h], w1 = w[(j + 1) * 4 + h];
        float g0 = hp[(size_t)s0 * 256];
        float g1 = hp[(size_t)s1 * 256];
        denom += w0 + w1;
        acc += w0 * g0 + w1 * g1;
    }
    if (j < end) {
        int s0 = col_src[j];
        float w0 = w[j * 4 + h];
        denom += w0;
        acc += w0 * hp[(size_t)s0 * 256];
    }
    float r = acc / (denom + 1e-16f) + b1[h * HID + lane];
    out1[(size_t)n * 256 + h * HID + lane] = (r > 0.f) ? r : (__expf(r) - 1.f);
}

// layer 2: heads=1, 4 nodes per block (one wave each); lane = channel.
__global__ void k_agg2(const float* __restrict__ h2, const int* __restrict__ row_ptr,
                       const int* __restrict__ col_src, const float* __restrict__ w,
                       const float* __restrict__ b2, float* __restrict__ out) {
    int n = blockIdx.x * 4 + (threadIdx.x >> 6);
    int lane = threadIdx.x & 63;
    if (n >= NNODES) return;
    int beg = row_ptr[n], end = row_ptr[n + 1];
    const float* hp = h2 + lane;

    float denom = 0.f, acc = 0.f;
    int j = beg;
    for (; j + 1 < end; j += 2) {
        int s0 = col_src[j], s1 = col_src[j + 1];
        float w0 = w[j], w1 = w[j + 1];
        float g0 = hp[(size_t)s0 * OUTC];
        float g1 = hp[(size_t)s1 * OUTC];
        denom += w0 + w1;
        acc += w0 * g0 + w1 * g1;
    }
    if (j < end) {
        int s0 = col_src[j];
        float w0 = w[j];
        denom += w0;
        acc += w0 * hp[(size_t)s0 * OUTC];
    }
    out[(size_t)n * OUTC + lane] = acc / (denom + 1e-16f) + b2[lane];
}

// ---------------- launch ----------------

extern "C" void kernel_launch(void* const* d_in, const int* in_sizes, int n_in,
                              void* d_out, int out_size, void* d_ws, size_t ws_size,
                              hipStream_t stream) {
    const float* x   = (const float*)d_in[0];
    const int*   ei  = (const int*)d_in[1];
    const float* W1  = (const float*)d_in[2];
    const float* a1s = (const float*)d_in[3];
    const float* a1d = (const float*)d_in[4];
    const float* b1  = (const float*)d_in[5];
    const float* W2  = (const float*)d_in[6];
    const float* a2s = (const float*)d_in[7];
    const float* a2d = (const float*)d_in[8];
    const float* b2  = (const float*)d_in[9];
    float* out = (float*)d_out;

    char* p = (char*)d_ws;
    auto carve = [&](size_t bytes) -> void* {
        void* r = (void*)p;
        p += (bytes + 255) & ~(size_t)255;
        return r;
    };
    float* h1      = (float*)carve((size_t)NNODES * 256 * 4);
    float* out1    = (float*)carve((size_t)NNODES * 256 * 4);
    float* h2      = (float*)carve((size_t)NNODES * 64 * 4);
    float* as1     = (float*)carve((size_t)NNODES * NHEADS * 4);
    float* ad1     = (float*)carve((size_t)NNODES * NHEADS * 4);
    float* as2     = (float*)carve((size_t)NNODES * 4);
    float* ad2     = (float*)carve((size_t)NNODES * 4);
    int*   row_ptr = (int*)carve((size_t)(NNODES + 1) * 4);
    int*   cursor  = (int*)carve((size_t)NNODES * 4);
    int*   col_src = (int*)carve((size_t)EPLUS * 4);
    int*   e_dst   = (int*)carve((size_t)EPLUS * 4);
    float* w1e     = (float*)carve((size_t)EPLUS * 4 * 4);
    float* w2e     = (float*)carve((size_t)EPLUS * 4);

    // CSR build
    hipMemsetAsync(row_ptr, 0, (size_t)(NNODES + 1) * 4, stream);
    k_count<<<(EPLUS + 255) / 256, 256, 0, stream>>>(ei, row_ptr);
    k_scan<<<1, 1024, 0, stream>>>(row_ptr);
    k_copy_int<<<(NNODES + 255) / 256, 256, 0, stream>>>(row_ptr, cursor, NNODES);
    k_scatter<<<(EPLUS + 255) / 256, 256, 0, stream>>>(ei, cursor, col_src, e_dst);

    // layer 1
    dim3 g1((NNODES + 63) / 64, 256 / 64);
    k_gemm<INC, 256><<<g1, 256, 0, stream>>>(x, W1, h1, NNODES);
    k_alpha1<<<(NNODES * NHEADS + 255) / 256, 256, 0, stream>>>(h1, a1s, a1d, as1, ad1);
    k_edgew1<<<(EPLUS + 255) / 256, 256, 0, stream>>>(col_src, e_dst, as1, ad1, w1e);
    k_agg1<<<NNODES, 256, 0, stream>>>(h1, row_ptr, col_src, w1e, b1, out1);

    // layer 2
    dim3 g2((NNODES + 63) / 64, 64 / 64);
    k_gemm<256, OUTC><<<g2, 256, 0, stream>>>(out1, W2, h2, NNODES);
    k_alpha2<<<(NNODES + 255) / 256, 256, 0, stream>>>(h2, a2s, a2d, as2, ad2);
    k_edgew2<<<(EPLUS + 255) / 256, 256, 0, stream>>>(col_src, e_dst, as2, ad2, w2e);
    k_agg2<<<(NNODES + 3) / 4, 256, 0, stream>>>(h2, row_ptr, col_src, w2e, b2, out);
}

// Round 3
// 509.281 us; speedup vs baseline: 1.4978x; 1.1069x over previous
//
#include <hip/hip_runtime.h>
#include <hip/hip_bf16.h>

#define NNODES 50000
#define NEDGES 800000
#define EPLUS  (NEDGES + NNODES)   // edges incl. self-loops = 850000
#define INC    128
#define HID    64
#define NHEADS 4
#define OUTC   64
#define NEG_SLOPE 0.2f

// ---------------- CSR build ----------------

__global__ void k_count(const int* __restrict__ ei, int* __restrict__ cnt) {
    int e = blockIdx.x * blockDim.x + threadIdx.x;
    if (e >= EPLUS) return;
    int dst = (e < NEDGES) ? ei[NEDGES + e] : (e - NEDGES);
    atomicAdd(&cnt[dst], 1);
}

// single-block exclusive scan over cnt[0..NNODES-1], writes cnt[NNODES] = total
__global__ void k_scan(int* __restrict__ cnt) {
    const int T = 1024;
    __shared__ int sums[T];
    int t = threadIdx.x;
    int L = (NNODES + T - 1) / T;            // 49
    int s0 = t * L;
    int s1 = s0 + L; if (s1 > NNODES) s1 = NNODES;
    int local = 0;
    for (int i = s0; i < s1; i++) local += cnt[i];
    sums[t] = local;
    __syncthreads();
    for (int off = 1; off < T; off <<= 1) {
        int v = (t >= off) ? sums[t - off] : 0;
        __syncthreads();
        sums[t] += v;
        __syncthreads();
    }
    int run = (t == 0) ? 0 : sums[t - 1];    // exclusive prefix
    for (int i = s0; i < s1; i++) { int c = cnt[i]; cnt[i] = run; run += c; }
    if (t == T - 1) cnt[NNODES] = sums[T - 1];
}

__global__ void k_copy_int(const int* __restrict__ src, int* __restrict__ dst, int n) {
    int i = blockIdx.x * blockDim.x + threadIdx.x;
    if (i < n) dst[i] = src[i];
}

__global__ void k_scatter(const int* __restrict__ ei, int* __restrict__ cursor,
                          int* __restrict__ col_src, int* __restrict__ e_dst) {
    int e = blockIdx.x * blockDim.x + threadIdx.x;
    if (e >= EPLUS) return;
    int src, dst;
    if (e < NEDGES) { src = ei[e]; dst = ei[NEDGES + e]; }
    else            { src = dst = e - NEDGES; }
    int pos = atomicAdd(&cursor[dst], 1);
    col_src[pos] = src;
    e_dst[pos] = dst;
}

// ---------------- fp32 tiled GEMM: C[M,NCOL] = A[M,K] @ B[K,NCOL] ----------------
// BM=64 BN=64 BK=32, 256 threads, 4x4 micro-tile per thread.
// Also writes a bf16 copy Cb (gather-side array for the aggregation kernels).

template <int K, int NCOL>
__global__ void k_gemm(const float* __restrict__ A, const float* __restrict__ B,
                       float* __restrict__ C, __hip_bfloat16* __restrict__ Cb, int M) {
    __shared__ float As[64][33];
    __shared__ float Bs[32][64];
    int tid = threadIdx.x;
    int row0 = blockIdx.x * 64;
    int col0 = blockIdx.y * 64;
    int tx = tid & 15, ty = tid >> 4;

    float acc[4][4];
#pragma unroll
    for (int i = 0; i < 4; i++)
#pragma unroll
        for (int j = 0; j < 4; j++) acc[i][j] = 0.f;

    int ar = tid >> 2, ac = (tid & 3) << 3;   // A: 8 consecutive floats
    int br = tid >> 3, bc = (tid & 7) << 3;   // B: 8 consecutive floats

    for (int k0 = 0; k0 < K; k0 += 32) {
        int grow = row0 + ar;
        if (grow < M) {
            const float* ap = A + (size_t)grow * K + k0 + ac;
            float4 a0 = *(const float4*)ap;
            float4 a1 = *(const float4*)(ap + 4);
            As[ar][ac + 0] = a0.x; As[ar][ac + 1] = a0.y; As[ar][ac + 2] = a0.z; As[ar][ac + 3] = a0.w;
            As[ar][ac + 4] = a1.x; As[ar][ac + 5] = a1.y; As[ar][ac + 6] = a1.z; As[ar][ac + 7] = a1.w;
        } else {
#pragma unroll
            for (int j = 0; j < 8; j++) As[ar][ac + j] = 0.f;
        }
        {
            const float* bp = B + (size_t)(k0 + br) * NCOL + col0 + bc;
            float4 b0 = *(const float4*)bp;
            float4 b1 = *(const float4*)(bp + 4);
            Bs[br][bc + 0] = b0.x; Bs[br][bc + 1] = b0.y; Bs[br][bc + 2] = b0.z; Bs[br][bc + 3] = b0.w;
            Bs[br][bc + 4] = b1.x; Bs[br][bc + 5] = b1.y; Bs[br][bc + 6] = b1.z; Bs[br][bc + 7] = b1.w;
        }
        __syncthreads();
#pragma unroll
        for (int kk = 0; kk < 32; kk++) {
            float a[4];
#pragma unroll
            for (int i = 0; i < 4; i++) a[i] = As[ty * 4 + i][kk];
            float4 bv = *(const float4*)&Bs[kk][tx * 4];
            float b[4] = {bv.x, bv.y, bv.z, bv.w};
#pragma unroll
            for (int i = 0; i < 4; i++)
#pragma unroll
                for (int j = 0; j < 4; j++) acc[i][j] += a[i] * b[j];
        }
        __syncthreads();
    }
#pragma unroll
    for (int i = 0; i < 4; i++) {
        int r = row0 + ty * 4 + i;
        if (r < M) {
            float4 v = {acc[i][0], acc[i][1], acc[i][2], acc[i][3]};
            *(float4*)&C[(size_t)r * NCOL + col0 + tx * 4] = v;
            __hip_bfloat16 bv[4];
            bv[0] = __float2bfloat16(v.x); bv[1] = __float2bfloat16(v.y);
            bv[2] = __float2bfloat16(v.z); bv[3] = __float2bfloat16(v.w);
            *(ulong1*)&Cb[(size_t)r * NCOL + col0 + tx * 4] = *(ulong1*)bv;
        }
    }
}

// ---------------- attention logits ----------------

__global__ void k_alpha1(const float* __restrict__ h1, const float* __restrict__ a_src,
                         const float* __restrict__ a_dst, float* __restrict__ as,
                         float* __restrict__ ad) {
    int i = blockIdx.x * blockDim.x + threadIdx.x;
    if (i >= NNODES * NHEADS) return;
    int n = i / NHEADS, h = i % NHEADS;
    const float* hp = h1 + (size_t)n * (NHEADS * HID) + h * HID;
    const float* ps = a_src + h * HID;
    const float* pd = a_dst + h * HID;
    float s = 0.f, d = 0.f;
#pragma unroll 8
    for (int c = 0; c < HID; c++) { float v = hp[c]; s += v * ps[c]; d += v * pd[c]; }
    as[i] = s; ad[i] = d;
}

__global__ void k_alpha2(const float* __restrict__ h2, const float* __restrict__ a_src,
                         const float* __restrict__ a_dst, float* __restrict__ as,
                         float* __restrict__ ad) {
    int n = blockIdx.x * blockDim.x + threadIdx.x;
    if (n >= NNODES) return;
    const float* hp = h2 + (size_t)n * OUTC;
    float s = 0.f, d = 0.f;
#pragma unroll 8
    for (int c = 0; c < OUTC; c++) { float v = hp[c]; s += v * a_src[c]; d += v * a_dst[c]; }
    as[n] = s; ad[n] = d;
}

// ---------------- edge weights: w = exp(leaky_relu(as[src] + ad[dst])) ----------------
// No max subtraction: logits are O(+-6) (glorot-scaled dots), exp is safe in fp32
// and the normalization below makes the result mathematically identical.

__global__ void k_edgew1(const int* __restrict__ col_src, const int* __restrict__ e_dst,
                         const float* __restrict__ as, const float* __restrict__ ad,
                         float* __restrict__ w) {
    int e = blockIdx.x * blockDim.x + threadIdx.x;
    if (e >= EPLUS) return;
    int s = col_src[e], d = e_dst[e];
    float4 sv = *(const float4*)&as[s * NHEADS];
    float4 dv = *(const float4*)&ad[d * NHEADS];
    float4 r;
    float t;
    t = sv.x + dv.x; t = (t > 0.f) ? t : NEG_SLOPE * t; r.x = __expf(t);
    t = sv.y + dv.y; t = (t > 0.f) ? t : NEG_SLOPE * t; r.y = __expf(t);
    t = sv.z + dv.z; t = (t > 0.f) ? t : NEG_SLOPE * t; r.z = __expf(t);
    t = sv.w + dv.w; t = (t > 0.f) ? t : NEG_SLOPE * t; r.w = __expf(t);
    *(float4*)&w[e * 4] = r;
}

__global__ void k_edgew2(const int* __restrict__ col_src, const int* __restrict__ e_dst,
                         const float* __restrict__ as, const float* __restrict__ ad,
                         float* __restrict__ w) {
    int e = blockIdx.x * blockDim.x + threadIdx.x;
    if (e >= EPLUS) return;
    float t = as[col_src[e]] + ad[e_dst[e]];
    t = (t > 0.f) ? t : NEG_SLOPE * t;
    w[e] = __expf(t);
}

// ---------------- aggregate (weights precomputed, bf16 gather) ----------------
// layer 1: one block per node, wave h handles head h; lane = channel.

__global__ void k_agg1(const __hip_bfloat16* __restrict__ h1b, const int* __restrict__ row_ptr,
                       const int* __restrict__ col_src, const float* __restrict__ w,
                       const float* __restrict__ b1, float* __restrict__ out1) {
    int n = blockIdx.x;
    int h = threadIdx.x >> 6;
    int lane = threadIdx.x & 63;
    int beg = row_ptr[n], end = row_ptr[n + 1];
    const __hip_bfloat16* hp = h1b + h * HID + lane;

    float denom = 0.f, acc = 0.f;
    int j = beg;
    for (; j + 3 < end; j += 4) {
        int s0 = col_src[j], s1 = col_src[j + 1], s2 = col_src[j + 2], s3 = col_src[j + 3];
        float w0 = w[j * 4 + h], w1 = w[(j + 1) * 4 + h];
        float w2 = w[(j + 2) * 4 + h], w3 = w[(j + 3) * 4 + h];
        float g0 = __bfloat162float(hp[(size_t)s0 * 256]);
        float g1 = __bfloat162float(hp[(size_t)s1 * 256]);
        float g2 = __bfloat162float(hp[(size_t)s2 * 256]);
        float g3 = __bfloat162float(hp[(size_t)s3 * 256]);
        denom += (w0 + w1) + (w2 + w3);
        acc += w0 * g0 + w1 * g1 + w2 * g2 + w3 * g3;
    }
    for (; j < end; j++) {
        int s0 = col_src[j];
        float w0 = w[j * 4 + h];
        denom += w0;
        acc += w0 * __bfloat162float(hp[(size_t)s0 * 256]);
    }
    float r = acc / (denom + 1e-16f) + b1[h * HID + lane];
    out1[(size_t)n * 256 + h * HID + lane] = (r > 0.f) ? r : (__expf(r) - 1.f);
}

// layer 2: heads=1, 4 nodes per block (one wave each); lane = channel.
__global__ void k_agg2(const __hip_bfloat16* __restrict__ h2b, const int* __restrict__ row_ptr,
                       const int* __restrict__ col_src, const float* __restrict__ w,
                       const float* __restrict__ b2, float* __restrict__ out) {
    int n = blockIdx.x * 4 + (threadIdx.x >> 6);
    int lane = threadIdx.x & 63;
    if (n >= NNODES) return;
    int beg = row_ptr[n], end = row_ptr[n + 1];
    const __hip_bfloat16* hp = h2b + lane;

    float denom = 0.f, acc = 0.f;
    int j = beg;
    for (; j + 3 < end; j += 4) {
        int s0 = col_src[j], s1 = col_src[j + 1], s2 = col_src[j + 2], s3 = col_src[j + 3];
        float w0 = w[j], w1 = w[j + 1], w2 = w[j + 2], w3 = w[j + 3];
        float g0 = __bfloat162float(hp[(size_t)s0 * OUTC]);
        float g1 = __bfloat162float(hp[(size_t)s1 * OUTC]);
        float g2 = __bfloat162float(hp[(size_t)s2 * OUTC]);
        float g3 = __bfloat162float(hp[(size_t)s3 * OUTC]);
        denom += (w0 + w1) + (w2 + w3);
        acc += w0 * g0 + w1 * g1 + w2 * g2 + w3 * g3;
    }
    for (; j < end; j++) {
        int s0 = col_src[j];
        float w0 = w[j];
        denom += w0;
        acc += w0 * __bfloat162float(hp[(size_t)s0 * OUTC]);
    }
    out[(size_t)n * OUTC + lane] = acc / (denom + 1e-16f) + b2[lane];
}

// ---------------- launch ----------------

extern "C" void kernel_launch(void* const* d_in, const int* in_sizes, int n_in,
                              void* d_out, int out_size, void* d_ws, size_t ws_size,
                              hipStream_t stream) {
    const float* x   = (const float*)d_in[0];
    const int*   ei  = (const int*)d_in[1];
    const float* W1  = (const float*)d_in[2];
    const float* a1s = (const float*)d_in[3];
    const float* a1d = (const float*)d_in[4];
    const float* b1  = (const float*)d_in[5];
    const float* W2  = (const float*)d_in[6];
    const float* a2s = (const float*)d_in[7];
    const float* a2d = (const float*)d_in[8];
    const float* b2  = (const float*)d_in[9];
    float* out = (float*)d_out;

    char* p = (char*)d_ws;
    auto carve = [&](size_t bytes) -> void* {
        void* r = (void*)p;
        p += (bytes + 255) & ~(size_t)255;
        return r;
    };
    float* h1      = (float*)carve((size_t)NNODES * 256 * 4);
    float* out1    = (float*)carve((size_t)NNODES * 256 * 4);
    float* h2      = (float*)carve((size_t)NNODES * 64 * 4);
    __hip_bfloat16* h1b = (__hip_bfloat16*)carve((size_t)NNODES * 256 * 2);
    __hip_bfloat16* h2b = (__hip_bfloat16*)carve((size_t)NNODES * 64 * 2);
    float* as1     = (float*)carve((size_t)NNODES * NHEADS * 4);
    float* ad1     = (float*)carve((size_t)NNODES * NHEADS * 4);
    float* as2     = (float*)carve((size_t)NNODES * 4);
    float* ad2     = (float*)carve((size_t)NNODES * 4);
    int*   row_ptr = (int*)carve((size_t)(NNODES + 1) * 4);
    int*   cursor  = (int*)carve((size_t)NNODES * 4);
    int*   col_src = (int*)carve((size_t)EPLUS * 4);
    int*   e_dst   = (int*)carve((size_t)EPLUS * 4);
    float* w1e     = (float*)carve((size_t)EPLUS * 4 * 4);
    float* w2e     = (float*)carve((size_t)EPLUS * 4);

    // CSR build
    hipMemsetAsync(row_ptr, 0, (size_t)(NNODES + 1) * 4, stream);
    k_count<<<(EPLUS + 255) / 256, 256, 0, stream>>>(ei, row_ptr);
    k_scan<<<1, 1024, 0, stream>>>(row_ptr);
    k_copy_int<<<(NNODES + 255) / 256, 256, 0, stream>>>(row_ptr, cursor, NNODES);
    k_scatter<<<(EPLUS + 255) / 256, 256, 0, stream>>>(ei, cursor, col_src, e_dst);

    // layer 1
    dim3 g1((NNODES + 63) / 64, 256 / 64);
    k_gemm<INC, 256><<<g1, 256, 0, stream>>>(x, W1, h1, h1b, NNODES);
    k_alpha1<<<(NNODES * NHEADS + 255) / 256, 256, 0, stream>>>(h1, a1s, a1d, as1, ad1);
    k_edgew1<<<(EPLUS + 255) / 256, 256, 0, stream>>>(col_src, e_dst, as1, ad1, w1e);
    k_agg1<<<NNODES, 256, 0, stream>>>(h1b, row_ptr, col_src, w1e, b1, out1);

    // layer 2
    dim3 g2((NNODES + 63) / 64, 64 / 64);
    k_gemm<256, OUTC><<<g2, 256, 0, stream>>>(out1, W2, h2, h2b, NNODES);
    k_alpha2<<<(NNODES + 255) / 256, 256, 0, stream>>>(h2, a2s, a2d, as2, ad2);
    k_edgew2<<<(EPLUS + 255) / 256, 256, 0, stream>>>(col_src, e_dst, as2, ad2, w2e);
    k_agg2<<<(NNODES + 3) / 4, 256, 0, stream>>>(h2b, row_ptr, col_src, w2e, b2, out);
}

// Round 4
// 473.194 us; speedup vs baseline: 1.6121x; 1.0763x over previous
//
#include <hip/hip_runtime.h>
#include <hip/hip_bf16.h>

#define NNODES 50000
#define NEDGES 800000
#define EPLUS  (NEDGES + NNODES)   // edges incl. self-loops = 850000
#define INC    128
#define HID    64
#define NHEADS 4
#define OUTC   64
#define NEG_SLOPE 0.2f

typedef __attribute__((ext_vector_type(8))) short short8;
typedef __attribute__((ext_vector_type(4))) float floatx4;

// ---------------- CSR build ----------------

__global__ void k_count(const int* __restrict__ ei, int* __restrict__ cnt) {
    int e = blockIdx.x * blockDim.x + threadIdx.x;
    if (e >= EPLUS) return;
    int dst = (e < NEDGES) ? ei[NEDGES + e] : (e - NEDGES);
    atomicAdd(&cnt[dst], 1);
}

__global__ void k_scan(int* __restrict__ cnt) {
    const int T = 1024;
    __shared__ int sums[T];
    int t = threadIdx.x;
    int L = (NNODES + T - 1) / T;
    int s0 = t * L;
    int s1 = s0 + L; if (s1 > NNODES) s1 = NNODES;
    int local = 0;
    for (int i = s0; i < s1; i++) local += cnt[i];
    sums[t] = local;
    __syncthreads();
    for (int off = 1; off < T; off <<= 1) {
        int v = (t >= off) ? sums[t - off] : 0;
        __syncthreads();
        sums[t] += v;
        __syncthreads();
    }
    int run = (t == 0) ? 0 : sums[t - 1];
    for (int i = s0; i < s1; i++) { int c = cnt[i]; cnt[i] = run; run += c; }
    if (t == T - 1) cnt[NNODES] = sums[T - 1];
}

__global__ void k_copy_int(const int* __restrict__ src, int* __restrict__ dst, int n) {
    int i = blockIdx.x * blockDim.x + threadIdx.x;
    if (i < n) dst[i] = src[i];
}

__global__ void k_scatter(const int* __restrict__ ei, int* __restrict__ cursor,
                          int* __restrict__ col_src, int* __restrict__ e_dst) {
    int e = blockIdx.x * blockDim.x + threadIdx.x;
    if (e >= EPLUS) return;
    int src, dst;
    if (e < NEDGES) { src = ei[e]; dst = ei[NEDGES + e]; }
    else            { src = dst = e - NEDGES; }
    int pos = atomicAdd(&cursor[dst], 1);
    col_src[pos] = src;
    e_dst[pos] = dst;
}

// ---------------- small prep kernels ----------------

// x (fp32) -> xb (bf16), 4 elems/thread
__global__ void k_cvt_x(const float* __restrict__ x, __hip_bfloat16* __restrict__ xb) {
    int i = blockIdx.x * blockDim.x + threadIdx.x;
    if (i >= NNODES * INC / 4) return;
    float4 v = *(const float4*)(x + (size_t)i * 4);
    __hip_bfloat16 o[4];
    o[0] = __float2bfloat16(v.x); o[1] = __float2bfloat16(v.y);
    o[2] = __float2bfloat16(v.z); o[3] = __float2bfloat16(v.w);
    *(ulong1*)(xb + (size_t)i * 4) = *(ulong1*)o;
}

// u_s[h][k] = sum_c W1[k][h*64+c] * a1s[h][c]   (and u_d likewise)
__global__ void k_uvec(const float* __restrict__ W1, const float* __restrict__ a1s,
                       const float* __restrict__ a1d, float* __restrict__ us,
                       float* __restrict__ ud) {
    int i = threadIdx.x + blockIdx.x * blockDim.x;   // 512 = 4 heads * 128 k
    if (i >= NHEADS * INC) return;
    int h = i >> 7, k = i & 127;
    const float* wp = W1 + (size_t)k * (NHEADS * HID) + h * HID;
    const float* sp = a1s + h * HID;
    const float* dp = a1d + h * HID;
    float s = 0.f, d = 0.f;
#pragma unroll 8
    for (int c = 0; c < HID; c++) { float w = wp[c]; s += w * sp[c]; d += w * dp[c]; }
    us[i] = s; ud[i] = d;
}

// as1[n,h] = x[n,:] . us[h,:]
__global__ void k_alpha1x(const float* __restrict__ x, const float* __restrict__ us,
                          const float* __restrict__ ud, float* __restrict__ as,
                          float* __restrict__ ad) {
    int i = blockIdx.x * blockDim.x + threadIdx.x;
    if (i >= NNODES * NHEADS) return;
    int n = i >> 2, h = i & 3;
    const float* xp = x + (size_t)n * INC;
    const float* sp = us + h * INC;
    const float* dp = ud + h * INC;
    float s = 0.f, d = 0.f;
#pragma unroll
    for (int c = 0; c < INC; c += 4) {
        float4 xv = *(const float4*)(xp + c);
        float4 sv = *(const float4*)(sp + c);
        float4 dv = *(const float4*)(dp + c);
        s += xv.x * sv.x + xv.y * sv.y + xv.z * sv.z + xv.w * sv.w;
        d += xv.x * dv.x + xv.y * dv.y + xv.z * dv.z + xv.w * dv.w;
    }
    as[i] = s; ad[i] = d;
}

// ---------------- edge weights ----------------
// No max subtraction: logits are O(+-6), exp safe in fp32; normalization below
// makes the result mathematically identical.

__global__ void k_edgew1(const int* __restrict__ col_src, const int* __restrict__ e_dst,
                         const float* __restrict__ as, const float* __restrict__ ad,
                         float* __restrict__ w) {
    int e = blockIdx.x * blockDim.x + threadIdx.x;
    if (e >= EPLUS) return;
    int s = col_src[e], d = e_dst[e];
    float4 sv = *(const float4*)&as[s * NHEADS];
    float4 dv = *(const float4*)&ad[d * NHEADS];
    float4 r;
    float t;
    t = sv.x + dv.x; t = (t > 0.f) ? t : NEG_SLOPE * t; r.x = __expf(t);
    t = sv.y + dv.y; t = (t > 0.f) ? t : NEG_SLOPE * t; r.y = __expf(t);
    t = sv.z + dv.z; t = (t > 0.f) ? t : NEG_SLOPE * t; r.z = __expf(t);
    t = sv.w + dv.w; t = (t > 0.f) ? t : NEG_SLOPE * t; r.w = __expf(t);
    *(float4*)&w[e * 4] = r;
}

__global__ void k_edgew2(const int* __restrict__ col_src, const int* __restrict__ e_dst,
                         const float* __restrict__ as, const float* __restrict__ ad,
                         float* __restrict__ w) {
    int e = blockIdx.x * blockDim.x + threadIdx.x;
    if (e >= EPLUS) return;
    float t = as[col_src[e]] + ad[e_dst[e]];
    t = (t > 0.f) ? t : NEG_SLOPE * t;
    w[e] = __expf(t);
}

// ---------------- layer-1 aggregation over x (pre-W1) ----------------
// agg[n,h,:] = (sum_e w[e,h] * x[src_e,:]) / (sum_e w[e,h])  -> bf16
// Block = 1 node, wave h = head h; lane handles channels lane*2, lane*2+1.

__global__ void k_agg1x(const __hip_bfloat16* __restrict__ xb, const int* __restrict__ row_ptr,
                        const int* __restrict__ col_src, const float* __restrict__ w,
                        __hip_bfloat16* __restrict__ aggb) {
    int n = blockIdx.x;
    int h = threadIdx.x >> 6;
    int lane = threadIdx.x & 63;
    int beg = row_ptr[n], end = row_ptr[n + 1];
    const unsigned* xp = (const unsigned*)(xb) + lane;   // pair of bf16 per lane

    float acc0 = 0.f, acc1 = 0.f, denom = 0.f;
    int j = beg;
    for (; j + 3 < end; j += 4) {
        int s0 = col_src[j], s1 = col_src[j + 1], s2 = col_src[j + 2], s3 = col_src[j + 3];
        float w0 = w[j * 4 + h], w1 = w[(j + 1) * 4 + h];
        float w2 = w[(j + 2) * 4 + h], w3 = w[(j + 3) * 4 + h];
        unsigned u0 = xp[(size_t)s0 * 64];
        unsigned u1 = xp[(size_t)s1 * 64];
        unsigned u2 = xp[(size_t)s2 * 64];
        unsigned u3 = xp[(size_t)s3 * 64];
        denom += (w0 + w1) + (w2 + w3);
        acc0 += w0 * __uint_as_float(u0 << 16) + w1 * __uint_as_float(u1 << 16)
              + w2 * __uint_as_float(u2 << 16) + w3 * __uint_as_float(u3 << 16);
        acc1 += w0 * __uint_as_float(u0 & 0xffff0000u) + w1 * __uint_as_float(u1 & 0xffff0000u)
              + w2 * __uint_as_float(u2 & 0xffff0000u) + w3 * __uint_as_float(u3 & 0xffff0000u);
    }
    for (; j < end; j++) {
        int s0 = col_src[j];
        float w0 = w[j * 4 + h];
        unsigned u0 = xp[(size_t)s0 * 64];
        denom += w0;
        acc0 += w0 * __uint_as_float(u0 << 16);
        acc1 += w0 * __uint_as_float(u0 & 0xffff0000u);
    }
    float inv = 1.f / (denom + 1e-16f);
    __hip_bfloat16 o[2];
    o[0] = __float2bfloat16(acc0 * inv);
    o[1] = __float2bfloat16(acc1 * inv);
    *(unsigned*)(aggb + ((size_t)n * NHEADS + h) * INC + lane * 2) = *(unsigned*)o;
}

// ---------------- weight swizzle into MFMA B-fragment order ----------------
// mfma_f32_16x16x32_bf16: B frag lane l holds B[k = s*32+(l>>4)*8+j][col], j=0..7

__global__ void k_swz1(const float* __restrict__ W1, __hip_bfloat16* __restrict__ Bsw) {
    int i = blockIdx.x * blockDim.x + threadIdx.x;   // [h][s][t][l][j]: 4*4*4*64*8
    if (i >= 4 * 4 * 4 * 64 * 8) return;
    int j = i & 7, l = (i >> 3) & 63, t = (i >> 9) & 3, s = (i >> 11) & 3, h = i >> 13;
    int k = s * 32 + (l >> 4) * 8 + j;
    int col = h * 64 + t * 16 + (l & 15);
    Bsw[i] = __float2bfloat16(W1[(size_t)k * 256 + col]);
}

__global__ void k_swz2(const float* __restrict__ W2, __hip_bfloat16* __restrict__ Bsw) {
    int i = blockIdx.x * blockDim.x + threadIdx.x;   // [s][t][l][j]: 8*4*64*8
    if (i >= 8 * 4 * 64 * 8) return;
    int j = i & 7, l = (i >> 3) & 63, t = (i >> 9) & 3, s = i >> 11;
    int k = s * 32 + (l >> 4) * 8 + j;
    int col = t * 16 + (l & 15);
    Bsw[i] = __float2bfloat16(W2[(size_t)k * 64 + col]);
}

// ---------------- MFMA GEMM 1': out1b = ELU(agg @ W1_h + b1) ----------------
// grid (M/64, 4 heads); 4 waves, wave w = 16 rows; cols = head h's 64.

__global__ void k_mm1(const __hip_bfloat16* __restrict__ A,   // [N][4][128] bf16
                      const __hip_bfloat16* __restrict__ Bsw, // [4][4][4][64][8]
                      const float* __restrict__ b1,
                      __hip_bfloat16* __restrict__ out1b) {
    int row0 = blockIdx.x * 64;
    int h = blockIdx.y;
    int w = threadIdx.x >> 6;
    int l = threadIdx.x & 63;
    int lg = l >> 4, lm = l & 15;
    int ra = row0 + w * 16 + lm;
    if (ra >= NNODES) ra = NNODES - 1;

    floatx4 acc[4];
#pragma unroll
    for (int t = 0; t < 4; t++) acc[t] = (floatx4){0.f, 0.f, 0.f, 0.f};

    const __hip_bfloat16* ap = A + ((size_t)ra * NHEADS + h) * INC + lg * 8;
#pragma unroll
    for (int s = 0; s < 4; s++) {
        short8 a = *(const short8*)(ap + s * 32);
#pragma unroll
        for (int t = 0; t < 4; t++) {
            short8 b = *(const short8*)(Bsw + (((h * 4 + s) * 4 + t) * 64 + l) * 8);
            acc[t] = __builtin_amdgcn_mfma_f32_16x16x32_bf16(a, b, acc[t], 0, 0, 0);
        }
    }
#pragma unroll
    for (int t = 0; t < 4; t++) {
        int col = h * 64 + t * 16 + lm;
        float bias = b1[col];
#pragma unroll
        for (int r = 0; r < 4; r++) {
            int row = row0 + w * 16 + lg * 4 + r;
            if (row < NNODES) {
                float v = acc[t][r] + bias;
                v = (v > 0.f) ? v : (__expf(v) - 1.f);
                out1b[(size_t)row * 256 + col] = __float2bfloat16(v);
            }
        }
    }
}

// ---------------- MFMA GEMM 2 + fused alpha2 ----------------
// h2 = out1 @ W2 (bf16 in, fp32 acc); writes h2b (bf16) and as2/ad2 = h2 . a2{s,d}

__global__ void k_mm2(const __hip_bfloat16* __restrict__ A,   // out1b [N][256]
                      const __hip_bfloat16* __restrict__ Bsw, // [8][4][64][8]
                      const float* __restrict__ a2s, const float* __restrict__ a2d,
                      __hip_bfloat16* __restrict__ h2b,
                      float* __restrict__ as2, float* __restrict__ ad2) {
    int row0 = blockIdx.x * 64;
    int w = threadIdx.x >> 6;
    int l = threadIdx.x & 63;
    int lg = l >> 4, lm = l & 15;
    int ra = row0 + w * 16 + lm;
    if (ra >= NNODES) ra = NNODES - 1;

    floatx4 acc[4];
#pragma unroll
    for (int t = 0; t < 4; t++) acc[t] = (floatx4){0.f, 0.f, 0.f, 0.f};

    const __hip_bfloat16* ap = A + (size_t)ra * 256 + lg * 8;
#pragma unroll
    for (int s = 0; s < 8; s++) {
        short8 a = *(const short8*)(ap + s * 32);
#pragma unroll
        for (int t = 0; t < 4; t++) {
            short8 b = *(const short8*)(Bsw + ((s * 4 + t) * 64 + l) * 8);
            acc[t] = __builtin_amdgcn_mfma_f32_16x16x32_bf16(a, b, acc[t], 0, 0, 0);
        }
    }
    float ps[4] = {0.f, 0.f, 0.f, 0.f};
    float pd[4] = {0.f, 0.f, 0.f, 0.f};
#pragma unroll
    for (int t = 0; t < 4; t++) {
        int col = t * 16 + lm;
        float vs = a2s[col], vd = a2d[col];
#pragma unroll
        for (int r = 0; r < 4; r++) {
            int row = row0 + w * 16 + lg * 4 + r;
            float v = acc[t][r];
            if (row < NNODES) h2b[(size_t)row * OUTC + col] = __float2bfloat16(v);
            ps[r] += v * vs;
            pd[r] += v * vd;
        }
    }
#pragma unroll
    for (int off = 1; off < 16; off <<= 1) {
#pragma unroll
        for (int r = 0; r < 4; r++) {
            ps[r] += __shfl_xor(ps[r], off, 64);
            pd[r] += __shfl_xor(pd[r], off, 64);
        }
    }
    if (lm == 0) {
#pragma unroll
        for (int r = 0; r < 4; r++) {
            int row = row0 + w * 16 + lg * 4 + r;
            if (row < NNODES) { as2[row] = ps[r]; ad2[row] = pd[r]; }
        }
    }
}

// ---------------- layer-2 aggregation ----------------
// heads=1, 4 nodes per block (one wave each); lane = channel.

__global__ void k_agg2(const __hip_bfloat16* __restrict__ h2b, const int* __restrict__ row_ptr,
                       const int* __restrict__ col_src, const float* __restrict__ w,
                       const float* __restrict__ b2, float* __restrict__ out) {
    int n = blockIdx.x * 4 + (threadIdx.x >> 6);
    int lane = threadIdx.x & 63;
    if (n >= NNODES) return;
    int beg = row_ptr[n], end = row_ptr[n + 1];
    const __hip_bfloat16* hp = h2b + lane;

    float denom = 0.f, acc = 0.f;
    int j = beg;
    for (; j + 3 < end; j += 4) {
        int s0 = col_src[j], s1 = col_src[j + 1], s2 = col_src[j + 2], s3 = col_src[j + 3];
        float w0 = w[j], w1 = w[j + 1], w2 = w[j + 2], w3 = w[j + 3];
        float g0 = __bfloat162float(hp[(size_t)s0 * OUTC]);
        float g1 = __bfloat162float(hp[(size_t)s1 * OUTC]);
        float g2 = __bfloat162float(hp[(size_t)s2 * OUTC]);
        float g3 = __bfloat162float(hp[(size_t)s3 * OUTC]);
        denom += (w0 + w1) + (w2 + w3);
        acc += w0 * g0 + w1 * g1 + w2 * g2 + w3 * g3;
    }
    for (; j < end; j++) {
        int s0 = col_src[j];
        float w0 = w[j];
        denom += w0;
        acc += w0 * __bfloat162float(hp[(size_t)s0 * OUTC]);
    }
    out[(size_t)n * OUTC + lane] = acc / (denom + 1e-16f) + b2[lane];
}

// ---------------- launch ----------------

extern "C" void kernel_launch(void* const* d_in, const int* in_sizes, int n_in,
                              void* d_out, int out_size, void* d_ws, size_t ws_size,
                              hipStream_t stream) {
    const float* x   = (const float*)d_in[0];
    const int*   ei  = (const int*)d_in[1];
    const float* W1  = (const float*)d_in[2];
    const float* a1s = (const float*)d_in[3];
    const float* a1d = (const float*)d_in[4];
    const float* b1  = (const float*)d_in[5];
    const float* W2  = (const float*)d_in[6];
    const float* a2s = (const float*)d_in[7];
    const float* a2d = (const float*)d_in[8];
    const float* b2  = (const float*)d_in[9];
    float* out = (float*)d_out;

    char* p = (char*)d_ws;
    auto carve = [&](size_t bytes) -> void* {
        void* r = (void*)p;
        p += (bytes + 255) & ~(size_t)255;
        return r;
    };
    __hip_bfloat16* xb    = (__hip_bfloat16*)carve((size_t)NNODES * INC * 2);
    __hip_bfloat16* aggb  = (__hip_bfloat16*)carve((size_t)NNODES * NHEADS * INC * 2);
    __hip_bfloat16* out1b = (__hip_bfloat16*)carve((size_t)NNODES * 256 * 2);
    __hip_bfloat16* h2b   = (__hip_bfloat16*)carve((size_t)NNODES * OUTC * 2);
    __hip_bfloat16* Bsw1  = (__hip_bfloat16*)carve((size_t)4 * 4 * 4 * 64 * 8 * 2);
    __hip_bfloat16* Bsw2  = (__hip_bfloat16*)carve((size_t)8 * 4 * 64 * 8 * 2);
    float* us      = (float*)carve((size_t)NHEADS * INC * 4);
    float* ud      = (float*)carve((size_t)NHEADS * INC * 4);
    float* as1     = (float*)carve((size_t)NNODES * NHEADS * 4);
    float* ad1     = (float*)carve((size_t)NNODES * NHEADS * 4);
    float* as2     = (float*)carve((size_t)NNODES * 4);
    float* ad2     = (float*)carve((size_t)NNODES * 4);
    int*   row_ptr = (int*)carve((size_t)(NNODES + 1) * 4);
    int*   cursor  = (int*)carve((size_t)NNODES * 4);
    int*   col_src = (int*)carve((size_t)EPLUS * 4);
    int*   e_dst   = (int*)carve((size_t)EPLUS * 4);
    float* w1e     = (float*)carve((size_t)EPLUS * 4 * 4);
    float* w2e     = (float*)carve((size_t)EPLUS * 4);

    // CSR build
    hipMemsetAsync(row_ptr, 0, (size_t)(NNODES + 1) * 4, stream);
    k_count<<<(EPLUS + 255) / 256, 256, 0, stream>>>(ei, row_ptr);
    k_scan<<<1, 1024, 0, stream>>>(row_ptr);
    k_copy_int<<<(NNODES + 255) / 256, 256, 0, stream>>>(row_ptr, cursor, NNODES);
    k_scatter<<<(EPLUS + 255) / 256, 256, 0, stream>>>(ei, cursor, col_src, e_dst);

    // prep
    k_cvt_x<<<(NNODES * INC / 4 + 255) / 256, 256, 0, stream>>>(x, xb);
    k_uvec<<<2, 256, 0, stream>>>(W1, a1s, a1d, us, ud);
    k_swz1<<<(4 * 4 * 4 * 64 * 8 + 255) / 256, 256, 0, stream>>>(W1, Bsw1);
    k_swz2<<<(8 * 4 * 64 * 8 + 255) / 256, 256, 0, stream>>>(W2, Bsw2);

    // layer 1
    k_alpha1x<<<(NNODES * NHEADS + 255) / 256, 256, 0, stream>>>(x, us, ud, as1, ad1);
    k_edgew1<<<(EPLUS + 255) / 256, 256, 0, stream>>>(col_src, e_dst, as1, ad1, w1e);
    k_agg1x<<<NNODES, 256, 0, stream>>>(xb, row_ptr, col_src, w1e, aggb);
    dim3 g1((NNODES + 63) / 64, NHEADS);
    k_mm1<<<g1, 256, 0, stream>>>(aggb, Bsw1, b1, out1b);

    // layer 2
    k_mm2<<<(NNODES + 63) / 64, 256, 0, stream>>>(out1b, Bsw2, a2s, a2d, h2b, as2, ad2);
    k_edgew2<<<(EPLUS + 255) / 256, 256, 0, stream>>>(col_src, e_dst, as2, ad2, w2e);
    k_agg2<<<(NNODES + 3) / 4, 256, 0, stream>>>(h2b, row_ptr, col_src, w2e, b2, out);
}

// Round 5
// 472.452 us; speedup vs baseline: 1.6146x; 1.0016x over previous
//
#include <hip/hip_runtime.h>
#include <hip/hip_bf16.h>

#define NNODES 50000
#define NEDGES 800000
#define EPLUS  (NEDGES + NNODES)   // edges incl. self-loops = 850000
#define INC    128
#define HID    64
#define NHEADS 4
#define OUTC   64
#define NEG_SLOPE 0.2f

typedef __attribute__((ext_vector_type(8))) short short8;
typedef __attribute__((ext_vector_type(4))) float floatx4;

// ---------------- CSR build ----------------

__global__ void k_count(const int* __restrict__ ei, int* __restrict__ cnt) {
    int e = blockIdx.x * blockDim.x + threadIdx.x;
    if (e >= EPLUS) return;
    int dst = (e < NEDGES) ? ei[NEDGES + e] : (e - NEDGES);
    atomicAdd(&cnt[dst], 1);
}

__global__ void k_scan(int* __restrict__ cnt) {
    const int T = 1024;
    __shared__ int sums[T];
    int t = threadIdx.x;
    int L = (NNODES + T - 1) / T;
    int s0 = t * L;
    int s1 = s0 + L; if (s1 > NNODES) s1 = NNODES;
    int local = 0;
    for (int i = s0; i < s1; i++) local += cnt[i];
    sums[t] = local;
    __syncthreads();
    for (int off = 1; off < T; off <<= 1) {
        int v = (t >= off) ? sums[t - off] : 0;
        __syncthreads();
        sums[t] += v;
        __syncthreads();
    }
    int run = (t == 0) ? 0 : sums[t - 1];
    for (int i = s0; i < s1; i++) { int c = cnt[i]; cnt[i] = run; run += c; }
    if (t == T - 1) cnt[NNODES] = sums[T - 1];
}

__global__ void k_copy_int(const int* __restrict__ src, int* __restrict__ dst, int n) {
    int i = blockIdx.x * blockDim.x + threadIdx.x;
    if (i < n) dst[i] = src[i];
}

__global__ void k_scatter(const int* __restrict__ ei, int* __restrict__ cursor,
                          int* __restrict__ col_src) {
    int e = blockIdx.x * blockDim.x + threadIdx.x;
    if (e >= EPLUS) return;
    int src, dst;
    if (e < NEDGES) { src = ei[e]; dst = ei[NEDGES + e]; }
    else            { src = dst = e - NEDGES; }
    int pos = atomicAdd(&cursor[dst], 1);
    col_src[pos] = src;
}

// ---------------- prep: u-vectors ----------------
// u_s[h][k] = sum_c W1[k][h*64+c] * a1s[h][c]   (and u_d likewise)
__global__ void k_uvec(const float* __restrict__ W1, const float* __restrict__ a1s,
                       const float* __restrict__ a1d, float* __restrict__ us,
                       float* __restrict__ ud) {
    int i = threadIdx.x + blockIdx.x * blockDim.x;
    if (i >= NHEADS * INC) return;
    int h = i >> 7, k = i & 127;
    const float* wp = W1 + (size_t)k * (NHEADS * HID) + h * HID;
    const float* sp = a1s + h * HID;
    const float* dp = a1d + h * HID;
    float s = 0.f, d = 0.f;
#pragma unroll 8
    for (int c = 0; c < HID; c++) { float w = wp[c]; s += w * sp[c]; d += w * dp[c]; }
    us[i] = s; ud[i] = d;
}

// ---------------- prep: x -> bf16 + attention logits (fused) ----------------
// One wave per node: lane l covers channels 2l, 2l+1.
__global__ void k_prep_x(const float* __restrict__ x, const float* __restrict__ us,
                         const float* __restrict__ ud, __hip_bfloat16* __restrict__ xb,
                         float* __restrict__ as1, float* __restrict__ ad1) {
    int w = threadIdx.x >> 6;
    int lane = threadIdx.x & 63;
    int n = blockIdx.x * 4 + w;
    if (n >= NNODES) return;
    float2 xv = *(const float2*)(x + (size_t)n * INC + lane * 2);
    // store bf16 pair
    __hip_bfloat16 o[2];
    o[0] = __float2bfloat16(xv.x);
    o[1] = __float2bfloat16(xv.y);
    *(unsigned*)(xb + (size_t)n * INC + lane * 2) = *(unsigned*)o;
    // dot partials for 4 heads
    float ps[4], pd[4];
#pragma unroll
    for (int h = 0; h < 4; h++) {
        float2 sv = *(const float2*)(us + h * INC + lane * 2);
        float2 dv = *(const float2*)(ud + h * INC + lane * 2);
        ps[h] = xv.x * sv.x + xv.y * sv.y;
        pd[h] = xv.x * dv.x + xv.y * dv.y;
    }
#pragma unroll
    for (int off = 1; off < 64; off <<= 1) {
#pragma unroll
        for (int h = 0; h < 4; h++) {
            ps[h] += __shfl_xor(ps[h], off, 64);
            pd[h] += __shfl_xor(pd[h], off, 64);
        }
    }
    if (lane == 0) {
        float4 vs = {ps[0], ps[1], ps[2], ps[3]};
        float4 vd = {pd[0], pd[1], pd[2], pd[3]};
        *(float4*)&as1[n * 4] = vs;
        *(float4*)&ad1[n * 4] = vd;
    }
}

// ---------------- layer-1: fused edge-weight + aggregation over x ----------------
// Block = 1 node, 4 waves SPLIT the edge list (stride 4); each wave handles all
// 4 heads. agg[n,h,:] = (sum_e w_h(e) x[src_e,:]) / (sum_e w_h(e)) -> bf16.
// w_h(e) = exp(leaky_relu(as1[src][h] + ad1[n][h])) computed inline; no max
// subtraction (logits O(+-6), normalization makes it identical).

__global__ void k_agg1f(const __hip_bfloat16* __restrict__ xb, const int* __restrict__ row_ptr,
                        const int* __restrict__ col_src, const float* __restrict__ as1,
                        const float* __restrict__ ad1, __hip_bfloat16* __restrict__ aggb) {
    __shared__ float2 red[4][4][64];   // [wave][head][lane]
    __shared__ float dred[4][4];       // [wave][head]
    int n = blockIdx.x;
    int w = threadIdx.x >> 6;
    int lane = threadIdx.x & 63;
    int beg = row_ptr[n], end = row_ptr[n + 1];
    float4 adv = *(const float4*)&ad1[n * 4];
    const unsigned* xp = (const unsigned*)xb + lane;

    float accL[4] = {0.f, 0.f, 0.f, 0.f};
    float accH[4] = {0.f, 0.f, 0.f, 0.f};
    float den[4]  = {0.f, 0.f, 0.f, 0.f};

    int j = beg + w;
    int sNext = (j < end) ? col_src[j] : 0;
    for (; j < end; j += 4) {
        int s = sNext;
        if (j + 4 < end) sNext = col_src[j + 4];
        float4 a = *(const float4*)&as1[s * 4];
        unsigned u = xp[(size_t)s * 64];
        float t, wt[4];
        t = a.x + adv.x; t = fmaxf(t, NEG_SLOPE * t); wt[0] = __expf(t);
        t = a.y + adv.y; t = fmaxf(t, NEG_SLOPE * t); wt[1] = __expf(t);
        t = a.z + adv.z; t = fmaxf(t, NEG_SLOPE * t); wt[2] = __expf(t);
        t = a.w + adv.w; t = fmaxf(t, NEG_SLOPE * t); wt[3] = __expf(t);
        float lo = __uint_as_float(u << 16);
        float hi = __uint_as_float(u & 0xffff0000u);
#pragma unroll
        for (int h = 0; h < 4; h++) {
            accL[h] += wt[h] * lo;
            accH[h] += wt[h] * hi;
            den[h]  += wt[h];
        }
    }
#pragma unroll
    for (int h = 0; h < 4; h++) red[w][h][lane] = (float2){accL[h], accH[h]};
    if (lane == 0) {
        dred[w][0] = den[0]; dred[w][1] = den[1];
        dred[w][2] = den[2]; dred[w][3] = den[3];
    }
    __syncthreads();
    // wave w finalizes head w
    float2 r0 = red[0][w][lane], r1 = red[1][w][lane];
    float2 r2 = red[2][w][lane], r3 = red[3][w][lane];
    float L = (r0.x + r1.x) + (r2.x + r3.x);
    float H = (r0.y + r1.y) + (r2.y + r3.y);
    float D = (dred[0][w] + dred[1][w]) + (dred[2][w] + dred[3][w]);
    float inv = 1.f / (D + 1e-16f);
    __hip_bfloat16 o[2];
    o[0] = __float2bfloat16(L * inv);
    o[1] = __float2bfloat16(H * inv);
    *(unsigned*)(aggb + ((size_t)n * NHEADS + w) * INC + lane * 2) = *(unsigned*)o;
}

// ---------------- weight swizzle into MFMA B-fragment order ----------------
// mfma_f32_16x16x32_bf16: B frag lane l holds B[k = s*32+(l>>4)*8+j][col], j=0..7

__global__ void k_swz1(const float* __restrict__ W1, __hip_bfloat16* __restrict__ Bsw) {
    int i = blockIdx.x * blockDim.x + threadIdx.x;   // [h][s][t][l][j]: 4*4*4*64*8
    if (i >= 4 * 4 * 4 * 64 * 8) return;
    int j = i & 7, l = (i >> 3) & 63, t = (i >> 9) & 3, s = (i >> 11) & 3, h = i >> 13;
    int k = s * 32 + (l >> 4) * 8 + j;
    int col = h * 64 + t * 16 + (l & 15);
    Bsw[i] = __float2bfloat16(W1[(size_t)k * 256 + col]);
}

__global__ void k_swz2(const float* __restrict__ W2, __hip_bfloat16* __restrict__ Bsw) {
    int i = blockIdx.x * blockDim.x + threadIdx.x;   // [s][t][l][j]: 8*4*64*8
    if (i >= 8 * 4 * 64 * 8) return;
    int j = i & 7, l = (i >> 3) & 63, t = (i >> 9) & 3, s = i >> 11;
    int k = s * 32 + (l >> 4) * 8 + j;
    int col = t * 16 + (l & 15);
    Bsw[i] = __float2bfloat16(W2[(size_t)k * 64 + col]);
}

// ---------------- MFMA GEMM 1': out1b = ELU(agg @ W1_h + b1) ----------------

__global__ void k_mm1(const __hip_bfloat16* __restrict__ A,   // [N][4][128] bf16
                      const __hip_bfloat16* __restrict__ Bsw, // [4][4][4][64][8]
                      const float* __restrict__ b1,
                      __hip_bfloat16* __restrict__ out1b) {
    int row0 = blockIdx.x * 64;
    int h = blockIdx.y;
    int w = threadIdx.x >> 6;
    int l = threadIdx.x & 63;
    int lg = l >> 4, lm = l & 15;
    int ra = row0 + w * 16 + lm;
    if (ra >= NNODES) ra = NNODES - 1;

    floatx4 acc[4];
#pragma unroll
    for (int t = 0; t < 4; t++) acc[t] = (floatx4){0.f, 0.f, 0.f, 0.f};

    const __hip_bfloat16* ap = A + ((size_t)ra * NHEADS + h) * INC + lg * 8;
#pragma unroll
    for (int s = 0; s < 4; s++) {
        short8 a = *(const short8*)(ap + s * 32);
#pragma unroll
        for (int t = 0; t < 4; t++) {
            short8 b = *(const short8*)(Bsw + (((h * 4 + s) * 4 + t) * 64 + l) * 8);
            acc[t] = __builtin_amdgcn_mfma_f32_16x16x32_bf16(a, b, acc[t], 0, 0, 0);
        }
    }
#pragma unroll
    for (int t = 0; t < 4; t++) {
        int col = h * 64 + t * 16 + lm;
        float bias = b1[col];
#pragma unroll
        for (int r = 0; r < 4; r++) {
            int row = row0 + w * 16 + lg * 4 + r;
            if (row < NNODES) {
                float v = acc[t][r] + bias;
                v = (v > 0.f) ? v : (__expf(v) - 1.f);
                out1b[(size_t)row * 256 + col] = __float2bfloat16(v);
            }
        }
    }
}

// ---------------- MFMA GEMM 2 + fused alpha2 ----------------

__global__ void k_mm2(const __hip_bfloat16* __restrict__ A,   // out1b [N][256]
                      const __hip_bfloat16* __restrict__ Bsw, // [8][4][64][8]
                      const float* __restrict__ a2s, const float* __restrict__ a2d,
                      __hip_bfloat16* __restrict__ h2b,
                      float* __restrict__ as2, float* __restrict__ ad2) {
    int row0 = blockIdx.x * 64;
    int w = threadIdx.x >> 6;
    int l = threadIdx.x & 63;
    int lg = l >> 4, lm = l & 15;
    int ra = row0 + w * 16 + lm;
    if (ra >= NNODES) ra = NNODES - 1;

    floatx4 acc[4];
#pragma unroll
    for (int t = 0; t < 4; t++) acc[t] = (floatx4){0.f, 0.f, 0.f, 0.f};

    const __hip_bfloat16* ap = A + (size_t)ra * 256 + lg * 8;
#pragma unroll
    for (int s = 0; s < 8; s++) {
        short8 a = *(const short8*)(ap + s * 32);
#pragma unroll
        for (int t = 0; t < 4; t++) {
            short8 b = *(const short8*)(Bsw + ((s * 4 + t) * 64 + l) * 8);
            acc[t] = __builtin_amdgcn_mfma_f32_16x16x32_bf16(a, b, acc[t], 0, 0, 0);
        }
    }
    float ps[4] = {0.f, 0.f, 0.f, 0.f};
    float pd[4] = {0.f, 0.f, 0.f, 0.f};
#pragma unroll
    for (int t = 0; t < 4; t++) {
        int col = t * 16 + lm;
        float vs = a2s[col], vd = a2d[col];
#pragma unroll
        for (int r = 0; r < 4; r++) {
            int row = row0 + w * 16 + lg * 4 + r;
            float v = acc[t][r];
            if (row < NNODES) h2b[(size_t)row * OUTC + col] = __float2bfloat16(v);
            ps[r] += v * vs;
            pd[r] += v * vd;
        }
    }
#pragma unroll
    for (int off = 1; off < 16; off <<= 1) {
#pragma unroll
        for (int r = 0; r < 4; r++) {
            ps[r] += __shfl_xor(ps[r], off, 64);
            pd[r] += __shfl_xor(pd[r], off, 64);
        }
    }
    if (lm == 0) {
#pragma unroll
        for (int r = 0; r < 4; r++) {
            int row = row0 + w * 16 + lg * 4 + r;
            if (row < NNODES) { as2[row] = ps[r]; ad2[row] = pd[r]; }
        }
    }
}

// ---------------- layer-2: fused edge-weight + aggregation ----------------
// Block = 1 node, 4 waves split edges; lane = channel.

__global__ void k_agg2f(const __hip_bfloat16* __restrict__ h2b, const int* __restrict__ row_ptr,
                        const int* __restrict__ col_src, const float* __restrict__ as2,
                        const float* __restrict__ ad2, const float* __restrict__ b2,
                        float* __restrict__ out) {
    __shared__ float red[4][64];
    __shared__ float dred[4];
    int n = blockIdx.x;
    int w = threadIdx.x >> 6;
    int lane = threadIdx.x & 63;
    int beg = row_ptr[n], end = row_ptr[n + 1];
    float adv = ad2[n];
    const __hip_bfloat16* hp = h2b + lane;

    float acc = 0.f, den = 0.f;
    int j = beg + w;
    int sNext = (j < end) ? col_src[j] : 0;
    for (; j < end; j += 4) {
        int s = sNext;
        if (j + 4 < end) sNext = col_src[j + 4];
        float t = as2[s] + adv;
        t = fmaxf(t, NEG_SLOPE * t);
        float wt = __expf(t);
        float g = __bfloat162float(hp[(size_t)s * OUTC]);
        acc += wt * g;
        den += wt;
    }
    red[w][lane] = acc;
    if (lane == 0) dred[w] = den;
    __syncthreads();
    if (w == 0) {
        float S = (red[0][lane] + red[1][lane]) + (red[2][lane] + red[3][lane]);
        float D = (dred[0] + dred[1]) + (dred[2] + dred[3]);
        out[(size_t)n * OUTC + lane] = S / (D + 1e-16f) + b2[lane];
    }
}

// ---------------- launch ----------------

extern "C" void kernel_launch(void* const* d_in, const int* in_sizes, int n_in,
                              void* d_out, int out_size, void* d_ws, size_t ws_size,
                              hipStream_t stream) {
    const float* x   = (const float*)d_in[0];
    const int*   ei  = (const int*)d_in[1];
    const float* W1  = (const float*)d_in[2];
    const float* a1s = (const float*)d_in[3];
    const float* a1d = (const float*)d_in[4];
    const float* b1  = (const float*)d_in[5];
    const float* W2  = (const float*)d_in[6];
    const float* a2s = (const float*)d_in[7];
    const float* a2d = (const float*)d_in[8];
    const float* b2  = (const float*)d_in[9];
    float* out = (float*)d_out;

    char* p = (char*)d_ws;
    auto carve = [&](size_t bytes) -> void* {
        void* r = (void*)p;
        p += (bytes + 255) & ~(size_t)255;
        return r;
    };
    __hip_bfloat16* xb    = (__hip_bfloat16*)carve((size_t)NNODES * INC * 2);
    __hip_bfloat16* aggb  = (__hip_bfloat16*)carve((size_t)NNODES * NHEADS * INC * 2);
    __hip_bfloat16* out1b = (__hip_bfloat16*)carve((size_t)NNODES * 256 * 2);
    __hip_bfloat16* h2b   = (__hip_bfloat16*)carve((size_t)NNODES * OUTC * 2);
    __hip_bfloat16* Bsw1  = (__hip_bfloat16*)carve((size_t)4 * 4 * 4 * 64 * 8 * 2);
    __hip_bfloat16* Bsw2  = (__hip_bfloat16*)carve((size_t)8 * 4 * 64 * 8 * 2);
    float* us      = (float*)carve((size_t)NHEADS * INC * 4);
    float* ud      = (float*)carve((size_t)NHEADS * INC * 4);
    float* as1     = (float*)carve((size_t)NNODES * NHEADS * 4);
    float* ad1     = (float*)carve((size_t)NNODES * NHEADS * 4);
    float* as2     = (float*)carve((size_t)NNODES * 4);
    float* ad2     = (float*)carve((size_t)NNODES * 4);
    int*   row_ptr = (int*)carve((size_t)(NNODES + 1) * 4);
    int*   cursor  = (int*)carve((size_t)NNODES * 4);
    int*   col_src = (int*)carve((size_t)EPLUS * 4);

    // CSR build
    hipMemsetAsync(row_ptr, 0, (size_t)(NNODES + 1) * 4, stream);
    k_count<<<(EPLUS + 255) / 256, 256, 0, stream>>>(ei, row_ptr);
    k_scan<<<1, 1024, 0, stream>>>(row_ptr);
    k_copy_int<<<(NNODES + 255) / 256, 256, 0, stream>>>(row_ptr, cursor, NNODES);
    k_scatter<<<(EPLUS + 255) / 256, 256, 0, stream>>>(ei, cursor, col_src);

    // prep
    k_uvec<<<2, 256, 0, stream>>>(W1, a1s, a1d, us, ud);
    k_swz1<<<(4 * 4 * 4 * 64 * 8 + 255) / 256, 256, 0, stream>>>(W1, Bsw1);
    k_swz2<<<(8 * 4 * 64 * 8 + 255) / 256, 256, 0, stream>>>(W2, Bsw2);
    k_prep_x<<<(NNODES + 3) / 4, 256, 0, stream>>>(x, us, ud, xb, as1, ad1);

    // layer 1
    k_agg1f<<<NNODES, 256, 0, stream>>>(xb, row_ptr, col_src, as1, ad1, aggb);
    dim3 g1((NNODES + 63) / 64, NHEADS);
    k_mm1<<<g1, 256, 0, stream>>>(aggb, Bsw1, b1, out1b);

    // layer 2
    k_mm2<<<(NNODES + 63) / 64, 256, 0, stream>>>(out1b, Bsw2, a2s, a2d, h2b, as2, ad2);
    k_agg2f<<<NNODES, 256, 0, stream>>>(h2b, row_ptr, col_src, as2, ad2, b2, out);
}